// Round 5
// baseline (553.006 us; speedup 1.0000x reference)
//
#include <hip/hip_runtime.h>
#include <hip/hip_bf16.h>
#include <math.h>

#define BB 4
#define LL 512
#define VV 32128
#define AVV 32000
#define DD 768
#define V4 (VV / 4)   // 8032
#define D4 (DD / 4)   // 192

// ---------------- Kernel 1: per-row argmax of logits + gumbel ----------------
// One 256-thread block per (b,l) row. Reads 2 x V floats per row (float4).
__global__ __launch_bounds__(256) void k_argmax(const float* __restrict__ logits,
                                                const float* __restrict__ gu,
                                                int* __restrict__ hidx) {
    const int row = blockIdx.x;
    const float4* lg4 = (const float4*)(logits + (size_t)row * VV);
    const float4* gu4 = (const float4*)(gu + (size_t)row * VV);

    float bk = -INFINITY;
    int   bi = 0x7fffffff;

    for (int i = threadIdx.x; i < V4; i += 256) {
        float4 lv = lg4[i];
        float4 uv = gu4[i];
        // g = -log(-log(u)); accurate logf (v_log_f32 has poor abs error near u~1,
        // and those elements carry the largest keys).
        float k0 = lv.x - logf(-logf(uv.x));
        float k1 = lv.y - logf(-logf(uv.y));
        float k2 = lv.z - logf(-logf(uv.z));
        float k3 = lv.w - logf(-logf(uv.w));
        int i0 = i * 4;
        if (k0 > bk) { bk = k0; bi = i0; }
        if (k1 > bk) { bk = k1; bi = i0 + 1; }
        if (k2 > bk) { bk = k2; bi = i0 + 2; }
        if (k3 > bk) { bk = k3; bi = i0 + 3; }
    }

    // wave (64-lane) reduction; tie -> smaller index
    for (int off = 32; off > 0; off >>= 1) {
        float ok = __shfl_down(bk, off);
        int   oi = __shfl_down(bi, off);
        if (ok > bk || (ok == bk && oi < bi)) { bk = ok; bi = oi; }
    }

    __shared__ float sk[4];
    __shared__ int   si[4];
    const int wid = threadIdx.x >> 6;
    if ((threadIdx.x & 63) == 0) { sk[wid] = bk; si[wid] = bi; }
    __syncthreads();
    if (threadIdx.x == 0) {
        for (int w = 1; w < 4; ++w) {
            if (sk[w] > bk || (sk[w] == bk && si[w] < bi)) { bk = sk[w]; bi = si[w]; }
        }
        hidx[row] = bi;
    }
}

// ---------------- Kernel 2: per-(b,l) token selection ----------------
// One block per batch row b, 512 threads = L positions.
__global__ __launch_bounds__(512) void k_tokens(const int* __restrict__ rwrt,
                                                const int* __restrict__ psg_in,
                                                const int* __restrict__ hidx,
                                                int2* __restrict__ toks) {
    __shared__ int s[LL];
    const int b = blockIdx.x;
    const int l = threadIdx.x;

    const int rw = rwrt[b * LL + l];

    // shifts = sum(rwrt == 1)
    s[l] = (rw == 1) ? 1 : 0;
    __syncthreads();
    for (int off = LL / 2; off > 0; off >>= 1) {
        if (l < off) s[l] += s[l + off];
        __syncthreads();
    }
    const int shifts = s[0];
    __syncthreads();

    // pos = (l - shifts) mod L   (L = 512 pow2, & works for negatives)
    const int pos = (l - shifts) & (LL - 1);
    // psg = roll(psg_input, 1)[.., 0]=1
    const int psgv = (pos == 0) ? 1 : psg_in[b * LL + pos - 1];
    // flipped_mask = 1 - fliplr(rwrt)
    const int flip = 1 - rwrt[b * LL + (LL - 1 - pos)];
    const int trunc = flip * psgv;

    // flag = inclusive OR-scan of (trunc != 0), Hillis-Steele (read-all/sync/write-all)
    s[l] = (trunc != 0) ? 1 : 0;
    __syncthreads();
    for (int off = 1; off < LL; off <<= 1) {
        int v = (l >= off) ? s[l - off] : 0;
        __syncthreads();
        s[l] |= v;
        __syncthreads();
    }
    const int flag = s[l];

    const int h = hidx[b * LL + l];
    const int tokA = (rw != 0 && h < AVV) ? h : -1;   // masked main embedding
    const int tokP = flag ? trunc : -1;               // psg embedding (may be 0)
    toks[b * LL + l] = make_int2(tokA, tokP);
}

// ---------------- Kernel 3: gather embeddings, sum, store f32 ----------------
__global__ __launch_bounds__(192) void k_out(const float* __restrict__ emb,
                                             const int2* __restrict__ toks,
                                             float* __restrict__ out) {
    const int row = blockIdx.x;
    const int t = threadIdx.x;     // 0..191, one float4 of D=768
    const int2 tk = toks[row];

    float4 acc = make_float4(0.f, 0.f, 0.f, 0.f);
    if (tk.x >= 0) {
        float4 e = ((const float4*)(emb + (size_t)tk.x * DD))[t];
        acc.x += e.x; acc.y += e.y; acc.z += e.z; acc.w += e.w;
    }
    if (tk.y >= 0) {
        float4 e = ((const float4*)(emb + (size_t)tk.y * DD))[t];
        acc.x += e.x; acc.y += e.y; acc.z += e.z; acc.w += e.w;
    }
    ((float4*)out)[(size_t)row * D4 + t] = acc;   // OUTPUT IS FLOAT32 (ref returns f32)
}

extern "C" void kernel_launch(void* const* d_in, const int* in_sizes, int n_in,
                              void* d_out, int out_size, void* d_ws, size_t ws_size,
                              hipStream_t stream) {
    const float* logits = (const float*)d_in[0];
    const float* gu     = (const float*)d_in[1];
    const float* emb    = (const float*)d_in[2];
    const int*   rwrt   = (const int*)d_in[3];
    const int*   psg    = (const int*)d_in[4];
    float* out = (float*)d_out;

    int*  hidx = (int*)d_ws;
    int2* toks = (int2*)((char*)d_ws + BB * LL * sizeof(int));  // 8KB offset, aligned

    k_argmax<<<BB * LL, 256, 0, stream>>>(logits, gu, hidx);
    k_tokens<<<BB, LL, 0, stream>>>(rwrt, psg, hidx, toks);
    k_out<<<BB * LL, 192, 0, stream>>>(emb, toks, out);
}